// Round 1
// baseline (284.286 us; speedup 1.0000x reference)
//
#include <hip/hip_runtime.h>

// Adaptive avg-pool 28x28 -> 7x7 with channel-last output.
// x: [B=32, C=2048, 28, 28] fp32 ; out: [B, 49, C] fp32
// Each bin is exactly a 4x4 patch (28/7 == 4). Each aligned float4 along w
// lies entirely inside one w-bin, so per-float4 horizontal sum is a bin partial.
//
// One wave (64 lanes) per (b,c) image:
//   - image = 196 float4 (3136 B contiguous, 16B-aligned since 3136 = 196*16)
//   - lane l loads float4 f = l, l+64, l+128 (lanes 0..3 take tail f=192..195)
//     -> fully coalesced 1 KiB per instruction
//   - lds[f] = hsum(float4)  (partial of bin (i=f/28, j=f%7))
//   - lanes 0..48: bin(i,j) = lds[28i+j] + lds[28i+7+j] + lds[28i+14+j] + lds[28i+21+j]
//   - out[b*49*2048 + (i*7+j)*2048 + c] = bin / 16

#define CH 2048
#define BN 32
#define IMG_F4 196   // 784 floats / 4
#define OUT_PER_B (49 * CH)

__global__ __launch_bounds__(256) void upp_pool_kernel(const float* __restrict__ x,
                                                       float* __restrict__ out) {
    __shared__ float lds[4][200];   // 196 used + pad, one slab per wave

    const int wave = threadIdx.x >> 6;
    const int lane = threadIdx.x & 63;
    const int bc   = blockIdx.x * 4 + wave;          // (b*2048 + c), < 65536

    const float4* img = (const float4*)(x + (size_t)bc * 784);
    float* myLds = lds[wave];

    // Coalesced read + horizontal sum into LDS
    #pragma unroll
    for (int k = 0; k < 3; ++k) {
        const int f = k * 64 + lane;
        const float4 v = img[f];
        myLds[f] = (v.x + v.y) + (v.z + v.w);
    }
    if (lane < 4) {
        const int f = 192 + lane;
        const float4 v = img[f];
        myLds[f] = (v.x + v.y) + (v.z + v.w);
    }

    __syncthreads();

    // 49 lanes finish their bin and store
    if (lane < 49) {
        const int i = lane / 7;
        const int j = lane - i * 7;
        const int base = i * 28 + j;
        const float s = (myLds[base] + myLds[base + 7]) +
                        (myLds[base + 14] + myLds[base + 21]);
        const int b = bc >> 11;            // / 2048
        const int c = bc & (CH - 1);       // % 2048
        out[(size_t)b * OUT_PER_B + lane * CH + c] = s * (1.0f / 16.0f);
    }
}

extern "C" void kernel_launch(void* const* d_in, const int* in_sizes, int n_in,
                              void* d_out, int out_size, void* d_ws, size_t ws_size,
                              hipStream_t stream) {
    const float* x = (const float*)d_in[0];
    float* out = (float*)d_out;

    const int n_images = BN * CH;              // 65536 (b,c) pairs
    const int blocks = n_images / 4;           // 4 waves per block
    upp_pool_kernel<<<blocks, 256, 0, stream>>>(x, out);
}

// Round 2
// 281.572 us; speedup vs baseline: 1.0096x; 1.0096x over previous
//
#include <hip/hip_runtime.h>

// Adaptive avg-pool 28x28 -> 7x7, channel-last output.
// x: [B=32, C=2048, 28, 28] fp32 ; out: [B, 49, C] fp32
// 28/7 == 4, so each bin is an aligned 4x4 patch and each aligned float4
// along w lies entirely inside one w-bin.
//
// Block = (b, 64-channel tile), 4 waves.
//   - wave w sequentially processes images c0+16w .. c0+16w+15
//   - per image: wave loads 196 float4 (3136 B contiguous) as
//     lane, lane+64, lane+128 (+4-elem tail) -> 1 KiB/instruction coalesced
//   - hsum(float4) -> per-wave scratch[196]; 49 lanes combine 4 row-partials
//     -> res[p][cslot]  (pad 65: write banks (p+cslot)%32, 2-way max = free)
//   - epilogue: wave w stores rows p = w, w+4, ... as 256 B contiguous,
//     256 B-aligned stores (perfect write coalescing)

#define CH 2048
#define OUT_PER_B (49 * CH)

__global__ __launch_bounds__(256) void upp_pool_kernel(const float* __restrict__ x,
                                                       float* __restrict__ out) {
    __shared__ float scratch[4][200];   // per-wave image row-partials
    __shared__ float res[49][65];       // [bin][channel-slot], +1 pad

    const int wave = threadIdx.x >> 6;
    const int lane = threadIdx.x & 63;
    const int b    = blockIdx.x >> 5;          // 32 channel-tiles per b
    const int c0   = (blockIdx.x & 31) * 64;   // channel tile base

    float* myLds = scratch[wave];
    const float* imgBase = x + ((size_t)b * CH + c0 + wave * 16) * 784;

    // bin index for lanes 0..48
    const int bi   = lane / 7;
    const int bj   = lane - bi * 7;
    const int bofs = bi * 28 + bj;

    for (int it = 0; it < 16; ++it) {
        const float4* img = (const float4*)(imgBase + (size_t)it * 784);

        const float4 v0 = img[lane];
        const float4 v1 = img[lane + 64];
        const float4 v2 = img[lane + 128];
        myLds[lane]       = (v0.x + v0.y) + (v0.z + v0.w);
        myLds[lane + 64]  = (v1.x + v1.y) + (v1.z + v1.w);
        myLds[lane + 128] = (v2.x + v2.y) + (v2.z + v2.w);
        if (lane < 4) {
            const float4 v3 = img[192 + lane];
            myLds[192 + lane] = (v3.x + v3.y) + (v3.z + v3.w);
        }

        __syncthreads();   // order scratch write -> read (also keeps waves in step)

        if (lane < 49) {
            const float s = (myLds[bofs] + myLds[bofs + 7]) +
                            (myLds[bofs + 14] + myLds[bofs + 21]);
            res[lane][wave * 16 + it] = s * (1.0f / 16.0f);
        }

        __syncthreads();   // protect scratch WAR across iterations
    }

    // Epilogue: coalesced 256 B row stores. res fully written; last
    // __syncthreads above makes all waves' columns visible.
    float* outBase = out + (size_t)b * OUT_PER_B + c0;
    for (int p = wave; p < 49; p += 4) {
        outBase[(size_t)p * CH + lane] = res[p][lane];
    }
}

extern "C" void kernel_launch(void* const* d_in, const int* in_sizes, int n_in,
                              void* d_out, int out_size, void* d_ws, size_t ws_size,
                              hipStream_t stream) {
    const float* x = (const float*)d_in[0];
    float* out = (float*)d_out;

    // 32 batches x 32 channel-tiles (64 ch each) = 1024 blocks
    upp_pool_kernel<<<1024, 256, 0, stream>>>(x, out);
}